// Round 2
// baseline (125.418 us; speedup 1.0000x reference)
//
#include <hip/hip_runtime.h>
#include <stdint.h>

typedef unsigned short u16;
typedef float f32x4 __attribute__((ext_vector_type(4)));
typedef __bf16 bf16x8 __attribute__((ext_vector_type(8)));

#define N1 8192
#define N2 8192
#define D 128
#define LD 256    // [hi(128) | lo(128)] per row
#define BM 128
#define BN 128
#define KS 32     // K-step over original D
#define NKT 4     // D / KS

__device__ __forceinline__ u16 f32_to_bf16_rne(float f) {
    union { float f; uint32_t u; } v; v.f = f;
    uint32_t u = v.u;
    return (u16)((u + 0x7FFFu + ((u >> 16) & 1u)) >> 16);
}

__device__ __forceinline__ void gload_lds16(const void* g, void* l) {
    __builtin_amdgcn_global_load_lds(
        (const __attribute__((address_space(1))) uint32_t*)g,
        (__attribute__((address_space(3))) uint32_t*)l,
        16, 0, 0);
}

// ---- prepass: scale by 1/l, split f32 -> hi|lo bf16 (LD=256), row sumsq ----
__global__ void prep_kernel(const float* __restrict__ X1, const float* __restrict__ X2,
                            const float* __restrict__ log_l,
                            u16* __restrict__ As, u16* __restrict__ Bs,
                            float* __restrict__ nrm1, float* __restrict__ nrm2)
{
    int t = threadIdx.x;
    int wave = t >> 6, lane = t & 63;
    int gr = blockIdx.x * 4 + wave;
    const float* X; u16* S; float* nrm; int row;
    if (gr < N1) { X = X1; S = As; nrm = nrm1; row = gr; }
    else         { X = X2; S = Bs; nrm = nrm2; row = gr - N1; }
    int c0 = lane * 2;
    float2 x = *(const float2*)(X + (size_t)row * D + c0);
    float il0 = __expf(-log_l[c0]);
    float il1 = __expf(-log_l[c0 + 1]);
    float a0 = x.x * il0, a1 = x.y * il1;
    float ss = a0 * a0 + a1 * a1;
    #pragma unroll
    for (int o = 32; o > 0; o >>= 1) ss += __shfl_down(ss, o);
    if (lane == 0) nrm[row] = ss;
    u16 h0 = f32_to_bf16_rne(a0), h1 = f32_to_bf16_rne(a1);
    union { uint32_t u; float f; } hf0, hf1;
    hf0.u = (uint32_t)h0 << 16; hf1.u = (uint32_t)h1 << 16;
    u16 l0 = f32_to_bf16_rne(a0 - hf0.f), l1 = f32_to_bf16_rne(a1 - hf1.f);
    u16* base = S + (size_t)row * LD;
    *(uint32_t*)(base + c0)       = (uint32_t)h0 | ((uint32_t)h1 << 16);
    *(uint32_t*)(base + 128 + c0) = (uint32_t)l0 | ((uint32_t)l1 << 16);
}

// ---- main: 128x128 tile, 4 tiles (Ah,Al,Bh,Bl) per BK=32 step, 2-phase dbuf ----
// acc += ah.bh + al.bh + ah.bl  (drops lo.lo, ~1e-5 rel)
__global__ __launch_bounds__(256) void gemm_epi(
    const u16* __restrict__ As, const u16* __restrict__ Bs,
    const float* __restrict__ n1, const float* __restrict__ n2,
    const int* __restrict__ t1, const int* __restrict__ t2,
    const float* __restrict__ log_theta_l, const float* __restrict__ bparam,
    float* __restrict__ C)
{
    __shared__ u16 lds[2][4][BM * KS];   // 2 bufs x {Ah,Al,Bh,Bl} x 8KB = 64KB
    int t = threadIdx.x;
    int wave = t >> 6, lane = t & 63;
    int wr = wave >> 1, wc = wave & 1;   // 2x2 waves, 64x64 each

    // XCD-aware bijective swizzle (nwg = 4096, divisible by 8)
    int nwg = gridDim.x;
    int wg = blockIdx.x;
    int cpx = nwg >> 3;
    int swz = (wg & 7) * cpx + (wg >> 3);
    int tm = swz >> 6;
    int tn = swz & 63;

    f32x4 acc[4][4];
    #pragma unroll
    for (int i = 0; i < 4; ++i)
        #pragma unroll
        for (int j = 0; j < 4; ++j) acc[i][j] = (f32x4){0.f, 0.f, 0.f, 0.f};

    const u16* Ag = As + (size_t)(tm * BM) * LD;
    const u16* Bg = Bs + (size_t)(tn * BN) * LD;

    // staging: each thread covers 16B slots s0=t, s1=t+256 of each 512-slot tile
    int r0 = t >> 2,        cb0 = (t & 3) * 8;          // slot s0
    int r1 = (t + 256) >> 2, cb1 = (t & 3) * 8;         // slot s1 (s1&3 == t&3)

    #define STAGE(buf, kt)                                                        \
    {                                                                             \
        int kc = (kt) * KS;                                                       \
        char* lb = (char*)&lds[buf][0][0];                                        \
        gload_lds16(Ag + (size_t)r0 * LD +       kc + cb0, lb +         t * 16);  \
        gload_lds16(Ag + (size_t)r1 * LD +       kc + cb1, lb +  4096 + t * 16);  \
        gload_lds16(Ag + (size_t)r0 * LD + 128 + kc + cb0, lb +  8192 + t * 16);  \
        gload_lds16(Ag + (size_t)r1 * LD + 128 + kc + cb1, lb + 12288 + t * 16);  \
        gload_lds16(Bg + (size_t)r0 * LD +       kc + cb0, lb + 16384 + t * 16);  \
        gload_lds16(Bg + (size_t)r1 * LD +       kc + cb1, lb + 20480 + t * 16);  \
        gload_lds16(Bg + (size_t)r0 * LD + 128 + kc + cb0, lb + 24576 + t * 16);  \
        gload_lds16(Bg + (size_t)r1 * LD + 128 + kc + cb1, lb + 28672 + t * 16);  \
    }

    STAGE(0, 0);
    __syncthreads();
    int cur = 0;
    int lr = lane & 15, lg = lane >> 4;

    for (int kt = 0; kt < NKT; ++kt) {
        if (kt < NKT - 1) STAGE(cur ^ 1, kt + 1);

        bf16x8 ah[4], al[4], bh[4], bl[4];
        const u16* pAh = &lds[cur][0][0];
        const u16* pAl = &lds[cur][1][0];
        const u16* pBh = &lds[cur][2][0];
        const u16* pBl = &lds[cur][3][0];
        #pragma unroll
        for (int mi = 0; mi < 4; ++mi) {
            int off = (wr * 64 + mi * 16 + lr) * KS + lg * 8;
            ah[mi] = *(const bf16x8*)(pAh + off);
            al[mi] = *(const bf16x8*)(pAl + off);
        }
        #pragma unroll
        for (int ni = 0; ni < 4; ++ni) {
            int off = (wc * 64 + ni * 16 + lr) * KS + lg * 8;
            bh[ni] = *(const bf16x8*)(pBh + off);
            bl[ni] = *(const bf16x8*)(pBl + off);
        }
        #pragma unroll
        for (int mi = 0; mi < 4; ++mi)
            #pragma unroll
            for (int ni = 0; ni < 4; ++ni) {
                acc[mi][ni] = __builtin_amdgcn_mfma_f32_16x16x32_bf16(ah[mi], bh[ni], acc[mi][ni], 0, 0, 0);
                acc[mi][ni] = __builtin_amdgcn_mfma_f32_16x16x32_bf16(al[mi], bh[ni], acc[mi][ni], 0, 0, 0);
                acc[mi][ni] = __builtin_amdgcn_mfma_f32_16x16x32_bf16(ah[mi], bl[ni], acc[mi][ni], 0, 0, 0);
            }
        __syncthreads();
        cur ^= 1;
    }
    #undef STAGE

    // ---- epilogue: s = n1 + n2 - 2*dot; K = exp(log_theta - 0.5*s) * mask ----
    float log_theta = log_theta_l[0];
    float bb = bparam[0];
    float lam = fminf(fmaxf(2.f / (1.f + __expf(bb)) - 1.f, 0.f), 1.f);

    int rbase = tm * BM + wr * 64;
    int cbase = tn * BN + wc * 64;

    float n1r[16]; int t1r[16];
    #pragma unroll
    for (int mi = 0; mi < 4; ++mi)
        #pragma unroll
        for (int r = 0; r < 4; ++r) {
            int row = rbase + mi * 16 + lg * 4 + r;
            n1r[mi * 4 + r] = n1[row];
            t1r[mi * 4 + r] = t1[row];
        }
    float n2c[4]; int t2c[4];
    #pragma unroll
    for (int ni = 0; ni < 4; ++ni) {
        int col = cbase + ni * 16 + lr;
        n2c[ni] = n2[col];
        t2c[ni] = t2[col];
    }
    #pragma unroll
    for (int mi = 0; mi < 4; ++mi)
        #pragma unroll
        for (int ni = 0; ni < 4; ++ni)
            #pragma unroll
            for (int r = 0; r < 4; ++r) {
                int row = rbase + mi * 16 + lg * 4 + r;
                int col = cbase + ni * 16 + lr;
                float dot = acc[mi][ni][r];
                float s = fmaxf(n1r[mi * 4 + r] + n2c[ni] - 2.f * dot, 0.f);
                float k = __expf(fmaf(-0.5f, s, log_theta));
                if (t1r[mi * 4 + r] != t2c[ni]) k *= lam;
                C[(size_t)row * N2 + col] = k;
            }
}

// ---- fallback (ws too small): direct f32, exact diff form ----
__global__ void fallback_kernel(const float* __restrict__ X1v, const float* __restrict__ X2v,
                                const float* __restrict__ log_l,
                                const float* __restrict__ log_theta_l, const float* __restrict__ bp,
                                const int* __restrict__ t1, const int* __restrict__ t2,
                                float* __restrict__ C)
{
    __shared__ float sA[16][128];
    __shared__ float sB[16][128];
    __shared__ float sil[128];
    int tx = threadIdx.x, ty = threadIdx.y;
    int tid = ty * 16 + tx;
    int row0 = blockIdx.y * 16, col0 = blockIdx.x * 16;
    if (tid < 128) sil[tid] = __expf(-log_l[tid]);
    __syncthreads();
    for (int i = tid; i < 16 * 128; i += 256) {
        int r = i >> 7, c = i & 127;
        sA[r][c] = X1v[(size_t)(row0 + r) * D + c] * sil[c];
        sB[r][c] = X2v[(size_t)(col0 + r) * D + c] * sil[c];
    }
    __syncthreads();
    float s = 0.f;
    for (int k = 0; k < D; ++k) {
        float d = sA[ty][k] - sB[tx][k];
        s = fmaf(d, d, s);
    }
    float log_theta = log_theta_l[0];
    float bb = bp[0];
    float lam = fminf(fmaxf(2.f / (1.f + __expf(bb)) - 1.f, 0.f), 1.f);
    int row = row0 + ty, col = col0 + tx;
    float k = __expf(fmaf(-0.5f, fmaxf(s, 0.f), log_theta));
    if (t1[row] != t2[col]) k *= lam;
    C[(size_t)row * N2 + col] = k;
}

extern "C" void kernel_launch(void* const* d_in, const int* in_sizes, int n_in,
                              void* d_out, int out_size, void* d_ws, size_t ws_size,
                              hipStream_t stream)
{
    const float* X1 = (const float*)d_in[0];
    const float* X2 = (const float*)d_in[1];
    const float* log_l = (const float*)d_in[2];
    const float* log_theta = (const float*)d_in[3];
    const float* bp = (const float*)d_in[4];
    const int* t1 = (const int*)d_in[5];
    const int* t2 = (const int*)d_in[6];
    float* C = (float*)d_out;

    size_t szA = (size_t)N1 * LD * sizeof(u16);
    size_t szB = (size_t)N2 * LD * sizeof(u16);
    size_t need = szA + szB + (size_t)(N1 + N2) * sizeof(float);

    if (ws_size >= need) {
        u16* As = (u16*)d_ws;
        u16* Bs = (u16*)((char*)d_ws + szA);
        float* nrm1 = (float*)((char*)d_ws + szA + szB);
        float* nrm2 = nrm1 + N1;
        prep_kernel<<<(N1 + N2) / 4, 256, 0, stream>>>(X1, X2, log_l, As, Bs, nrm1, nrm2);
        gemm_epi<<<(N1 / BM) * (N2 / BN), 256, 0, stream>>>(As, Bs, nrm1, nrm2,
                                                            t1, t2, log_theta, bp, C);
    } else {
        dim3 blk(16, 16), grd(N2 / 16, N1 / 16);
        fallback_kernel<<<grd, blk, 0, stream>>>(X1, X2, log_l, log_theta, bp, t1, t2, C);
    }
}

// Round 3
// 117.540 us; speedup vs baseline: 1.0670x; 1.0670x over previous
//
#include <hip/hip_runtime.h>
#include <stdint.h>

typedef float f32x4 __attribute__((ext_vector_type(4)));
typedef __bf16 bf16x8 __attribute__((ext_vector_type(8)));

#define N1 8192
#define N2 8192
#define DD 128
#define BK 32

__device__ __forceinline__ void gload_lds16(const void* g, void* l) {
    __builtin_amdgcn_global_load_lds(
        (const __attribute__((address_space(1))) uint32_t*)g,
        (__attribute__((address_space(3))) uint32_t*)l,
        16, 0, 0);
}

// Single fused kernel: on-the-fly hi/lo bf16 split GEMM + norms + epilogue.
// LDS map: [0,64K) = 2 x {A f32 tile 16K | B f32 tile 16K} (stage, dbuf),
//          reused as f32 bounce buffer for the coalesced C store.
//          [64K, +512) ils, [+512,+1024) n1s, [+1024,+1536) n2s.
__global__ __launch_bounds__(256) void tgp_kernel(
    const float* __restrict__ X1, const float* __restrict__ X2,
    const float* __restrict__ log_l,
    const float* __restrict__ log_theta_l, const float* __restrict__ bparam,
    const int* __restrict__ t1, const int* __restrict__ t2,
    float* __restrict__ C)
{
    __shared__ __align__(128) char smem[65536 + 1536];
    float* const bounce = (float*)smem;
    float* const ils = (float*)(smem + 65536);
    float* const n1s = ils + 128;
    float* const n2s = ils + 256;

    const int t = threadIdx.x;
    const int lane = t & 63;
    const int wave = t >> 6;
    const int wr = wave >> 1, wc = wave & 1;     // 2x2 waves, 64x64 each
    const int lr = lane & 15, lg = lane >> 4;

    // XCD-aware bijective swizzle (nwg = 4096 = 8*512)
    int wg = blockIdx.x;
    int swz = (wg & 7) * 512 + (wg >> 3);
    int tm = swz >> 6, tn = swz & 63;

    const float* Ag = X1 + (size_t)(tm * 128) * DD;
    const float* Bg = X2 + (size_t)(tn * 128) * DD;

    f32x4 acc[4][4];
    #pragma unroll
    for (int i = 0; i < 4; ++i)
        #pragma unroll
        for (int j = 0; j < 4; ++j) acc[i][j] = (f32x4){0.f, 0.f, 0.f, 0.f};

    // Stage one BK=32 f32 K-slab of A and B. LDS dest is linear (lane-ordered,
    // rule #21); the XOR swizzle (unit ^ (row&7), 16B units) is applied to the
    // GLOBAL source so swizzled LDS reads are conflict-free.
    #define STAGE(buf, kt)                                                          \
    {                                                                               \
        char* lb = smem + (buf) * 32768;                                            \
        int slot, row, ul;                                                          \
        slot = t;       row = slot >> 3; ul = (slot & 7) ^ (row & 7);               \
        gload_lds16(Ag + (size_t)row * DD + (kt) * BK + ul * 4, lb + slot * 16);    \
        gload_lds16(Bg + (size_t)row * DD + (kt) * BK + ul * 4, lb + 16384 + slot * 16); \
        slot = t + 256; row = slot >> 3; ul = (slot & 7) ^ (row & 7);               \
        gload_lds16(Ag + (size_t)row * DD + (kt) * BK + ul * 4, lb + slot * 16);    \
        gload_lds16(Bg + (size_t)row * DD + (kt) * BK + ul * 4, lb + 16384 + slot * 16); \
        slot = t + 512; row = slot >> 3; ul = (slot & 7) ^ (row & 7);               \
        gload_lds16(Ag + (size_t)row * DD + (kt) * BK + ul * 4, lb + slot * 16);    \
        gload_lds16(Bg + (size_t)row * DD + (kt) * BK + ul * 4, lb + 16384 + slot * 16); \
        slot = t + 768; row = slot >> 3; ul = (slot & 7) ^ (row & 7);               \
        gload_lds16(Ag + (size_t)row * DD + (kt) * BK + ul * 4, lb + slot * 16);    \
        gload_lds16(Bg + (size_t)row * DD + (kt) * BK + ul * 4, lb + 16384 + slot * 16); \
    }

    STAGE(0, 0);
    if (t < 128) ils[t] = __expf(-log_l[t]);
    __syncthreads();

    float nrm_acc = 0.f;
    const int nrow = t & 127;
    const int nroff = (t < 128) ? 0 : 16384;   // A rows for waves 0-1, B for 2-3
    int cur = 0;

    for (int kt = 0; kt < 4; ++kt) {
        if (kt < 3) STAGE(cur ^ 1, kt + 1);

        const float* tA = (const float*)(smem + cur * 32768);
        const float* tB = tA + 4096;

        // ---- per-row norm partial (one row per thread, logical-order read) ----
        {
            const float* tp = (const float*)(smem + cur * 32768 + nroff);
            #pragma unroll
            for (int u = 0; u < 8; ++u) {
                int up = u ^ (nrow & 7);
                f32x4 x = *(const f32x4*)(tp + nrow * 32 + up * 4);
                f32x4 il = *(const f32x4*)(ils + kt * 32 + u * 4);
                f32x4 sx = x * il;
                nrm_acc += sx[0]*sx[0] + sx[1]*sx[1] + sx[2]*sx[2] + sx[3]*sx[3];
            }
        }

        // ---- fragment build: read f32 (swizzled), scale by 1/l, split hi/lo ----
        float il8[8];
        {
            f32x4 i0 = *(const f32x4*)(ils + kt * 32 + lg * 8);
            f32x4 i1 = *(const f32x4*)(ils + kt * 32 + lg * 8 + 4);
            il8[0]=i0[0]; il8[1]=i0[1]; il8[2]=i0[2]; il8[3]=i0[3];
            il8[4]=i1[0]; il8[5]=i1[1]; il8[6]=i1[2]; il8[7]=i1[3];
        }
        bf16x8 ah[4], al[4], bh[4], bl[4];
        #pragma unroll
        for (int mi = 0; mi < 4; ++mi) {
            int row = wr * 64 + mi * 16 + lr;
            int p0 = (2 * lg) ^ (row & 7), p1 = (2 * lg + 1) ^ (row & 7);
            f32x4 x0 = *(const f32x4*)(tA + row * 32 + p0 * 4);
            f32x4 x1 = *(const f32x4*)(tA + row * 32 + p1 * 4);
            float sv[8] = {x0[0]*il8[0], x0[1]*il8[1], x0[2]*il8[2], x0[3]*il8[3],
                           x1[0]*il8[4], x1[1]*il8[5], x1[2]*il8[6], x1[3]*il8[7]};
            #pragma unroll
            for (int e = 0; e < 8; ++e) {
                __bf16 h = (__bf16)sv[e];
                ah[mi][e] = h;
                al[mi][e] = (__bf16)(sv[e] - (float)h);
            }
        }
        #pragma unroll
        for (int ni = 0; ni < 4; ++ni) {
            int row = wc * 64 + ni * 16 + lr;
            int p0 = (2 * lg) ^ (row & 7), p1 = (2 * lg + 1) ^ (row & 7);
            f32x4 x0 = *(const f32x4*)(tB + row * 32 + p0 * 4);
            f32x4 x1 = *(const f32x4*)(tB + row * 32 + p1 * 4);
            float sv[8] = {x0[0]*il8[0], x0[1]*il8[1], x0[2]*il8[2], x0[3]*il8[3],
                           x1[0]*il8[4], x1[1]*il8[5], x1[2]*il8[6], x1[3]*il8[7]};
            #pragma unroll
            for (int e = 0; e < 8; ++e) {
                __bf16 h = (__bf16)sv[e];
                bh[ni][e] = h;
                bl[ni][e] = (__bf16)(sv[e] - (float)h);
            }
        }

        // ---- MFMA, operands SWAPPED so lane owns 4 consecutive C-columns ----
        #pragma unroll
        for (int mi = 0; mi < 4; ++mi)
            #pragma unroll
            for (int ni = 0; ni < 4; ++ni) {
                acc[mi][ni] = __builtin_amdgcn_mfma_f32_16x16x32_bf16(bh[ni], ah[mi], acc[mi][ni], 0, 0, 0);
                acc[mi][ni] = __builtin_amdgcn_mfma_f32_16x16x32_bf16(bh[ni], al[mi], acc[mi][ni], 0, 0, 0);
                acc[mi][ni] = __builtin_amdgcn_mfma_f32_16x16x32_bf16(bl[ni], ah[mi], acc[mi][ni], 0, 0, 0);
            }
        __syncthreads();
        cur ^= 1;
    }
    #undef STAGE

    if (t < 128) n1s[t] = nrm_acc; else n2s[t - 128] = nrm_acc;
    __syncthreads();   // norms visible; stage LDS free for reuse as bounce

    // ---- epilogue: K = exp(logt - 0.5*max(n1+n2-2dot,0)) * mask ----
    float logt = log_theta_l[0];
    float bb = bparam[0];
    float lam = fminf(fmaxf(2.f / (1.f + __expf(bb)) - 1.f, 0.f), 1.f);
    int rbase = tm * 128, cbase = tn * 128;

    #pragma unroll
    for (int mi = 0; mi < 4; ++mi) {
        int rowl = wr * 64 + mi * 16 + lr;            // lane&15 = A-row (swapped)
        float n1v = n1s[rowl];
        int t1v = t1[rbase + rowl];
        #pragma unroll
        for (int ni = 0; ni < 4; ++ni) {
            int coll = wc * 64 + ni * 16 + lg * 4;    // reg r = 4 consecutive cols
            f32x4 kv;
            #pragma unroll
            for (int r = 0; r < 4; ++r) {
                float dot = acc[mi][ni][r];
                float n2v = n2s[coll + r];
                int t2v = t2[cbase + coll + r];
                float s = fmaxf(n1v + n2v - 2.f * dot, 0.f);
                float k = __expf(fmaf(-0.5f, s, logt));
                if (t1v != t2v) k *= lam;
                kv[r] = k;
            }
            int phys = rowl * 128 + (coll ^ ((rowl & 7) << 2));  // XOR-swizzled bounce
            *(f32x4*)(bounce + phys) = kv;
        }
    }
    __syncthreads();

    // ---- coalesced store: each wave-instr covers 2 full rows (1 KB contiguous) ----
    #pragma unroll
    for (int s2 = 0; s2 < 16; ++s2) {
        int lrow = s2 * 8 + (t >> 5);
        int lcol = (t & 31) * 4;
        int phys = lrow * 128 + (lcol ^ ((lrow & 7) << 2));
        f32x4 v = *(const f32x4*)(bounce + phys);
        *(f32x4*)(C + (size_t)(rbase + lrow) * N2 + (cbase + lcol)) = v;
    }
}

extern "C" void kernel_launch(void* const* d_in, const int* in_sizes, int n_in,
                              void* d_out, int out_size, void* d_ws, size_t ws_size,
                              hipStream_t stream)
{
    const float* X1 = (const float*)d_in[0];
    const float* X2 = (const float*)d_in[1];
    const float* log_l = (const float*)d_in[2];
    const float* log_theta = (const float*)d_in[3];
    const float* bp = (const float*)d_in[4];
    const int* t1 = (const int*)d_in[5];
    const int* t2 = (const int*)d_in[6];
    float* C = (float*)d_out;
    (void)d_ws; (void)ws_size; (void)in_sizes; (void)n_in; (void)out_size;

    tgp_kernel<<<4096, 256, 0, stream>>>(X1, X2, log_l, log_theta, bp, t1, t2, C);
}